// Round 13
// baseline (151.761 us; speedup 1.0000x reference)
//
#include <hip/hip_runtime.h>
#include <math.h>

// Problem constants (z: [16,4096,128] f32, emb_w: [1024,128] f32, unit rows)
#define D       128
#define NE      1024
#define NROWS   65536   // B*N
#define NB      16

// ---- output float offsets (total 16,924,675 floats) ----
#define OUT_ZQ    0            // [16,4096,128]
#define OUT_LOSS  8388608      // scalar
#define OUT_SAMP  8388609      // [16,1024]
#define OUT_IDX   8404993      // [16,4096] (float)
#define OUT_VAR   8470529      // scalar
#define OUT_DIST  8470530      // scalar
#define OUT_SI    8470531      // [16,4096] (float)
#define OUT_ZN    8536067      // [16,4096,128]  (overwritten LAST by k_zn)

// Scratch inside the OUT_ZN region (k_zn overwrites it at the very end).
#define SCR       8536068         // wh: 131072 ushorts (256KB)
#define SCR_WL    (SCR + 65536)   // wl: 131072 ushorts (256KB)
#define SCR_CNT   (SCR + 131072)  // int counter (zeroed by k_wsplit)
#define SCR_LIST  (SCR + 131073)  // int[<=65536] flagged-row list

// ---- workspace float offsets (538 KB total) ----
#define WS_IDX    0            // int[65536]
#define WS_WW     65536        // float[1024]
#define WS_FLAGS  66560        // int[1024]
#define WS_MIN2   67584        // float[1024]
#define WS_VAR    68608        // float[1024]
#define WS_LOSSP  69632        // float[512]
#define WS_COLSQP 70144        // float[512*128]
#define WS_COLSQ  135680       // float[16*128] (unused, kept for layout)

#define MARGIN 2e-3f

typedef __attribute__((ext_vector_type(8))) short s16x8;   // 8 bf16 (4 VGPR)
typedef __attribute__((ext_vector_type(4))) float f32x4;

#define GLDS16(gp, lp)                                                        \
  __builtin_amdgcn_global_load_lds(                                           \
      (const __attribute__((address_space(1))) unsigned int*)(gp),            \
      (__attribute__((address_space(3))) unsigned int*)(lp), 16, 0, 0)

__device__ __forceinline__ unsigned short f2bf(float f) {  // bf16 RNE
  unsigned int u = __float_as_uint(f);
  return (unsigned short)((u + 0x7FFFu + ((u >> 16) & 1u)) >> 16);
}
__device__ __forceinline__ float bf2f(unsigned short h) {
  return __uint_as_float(((unsigned int)h) << 16);
}

// numpy pairwise sum of squares over 128 contiguous floats (exact ref order).
__device__ __forceinline__ float npsq_sum128(const float* p) {
  float a[8];
#pragma unroll
  for (int m = 0; m < 8; ++m) a[m] = __fmul_rn(p[m], p[m]);
  for (int k = 8; k < 128; k += 8) {
#pragma unroll
    for (int m = 0; m < 8; ++m) a[m] = __fadd_rn(a[m], __fmul_rn(p[k + m], p[k + m]));
  }
  float s01 = __fadd_rn(a[0], a[1]);
  float s23 = __fadd_rn(a[2], a[3]);
  float s45 = __fadd_rn(a[4], a[5]);
  float s67 = __fadd_rn(a[6], a[7]);
  return __fadd_rn(__fadd_rn(s01, s23), __fadd_rn(s45, s67));
}

// ---- split w into bf16 hi/lo (full 4-bit XOR swizzle) + ww; also zero
// the flags array and the fallback counter (replaces both memsets). ----
// byte(c,k) = (c*256 + 2k) ^ ((c&15)<<4): 16B chunks -> 16B chunks.
__global__ __launch_bounds__(256) void k_wsplit(const float* __restrict__ w,
                                                float* __restrict__ out,
                                                float* __restrict__ ws) {
  int u = blockIdx.x * 256 + threadIdx.x;   // 16384 = 1024 codes x 16 octets
  int c = u >> 4, j = u & 15;
  const float4* p = (const float4*)(w + c * D + j * 8);
  float4 f0 = p[0], f1 = p[1];
  float ff[8] = {f0.x, f0.y, f0.z, f0.w, f1.x, f1.y, f1.z, f1.w};
  s16x8 h, l;
#pragma unroll
  for (int e = 0; e < 8; ++e) {
    unsigned short hb = f2bf(ff[e]);
    h[e] = (short)hb;
    l[e] = (short)f2bf(ff[e] - bf2f(hb));
  }
  unsigned int by = ((unsigned int)(c * 256 + j * 16)) ^ ((unsigned int)((c & 15) << 4));
  *(s16x8*)((char*)(out + SCR) + by)    = h;
  *(s16x8*)((char*)(out + SCR_WL) + by) = l;
  if (u < NE) {
    ws[WS_WW + u] = npsq_sum128(w + u * D);   // fused k_ww
    ((int*)ws)[WS_FLAGS + u] = 0;             // replaces memset #1
  }
  if (u == 0) ((int*)out)[SCR_CNT] = 0;       // replaces memset #2
}

// =====================================================================
// k_cb v3: codebook self-distance stats via 3-chain hi/lo MFMA
// (tolerance-checked scalar outputs -> no margin/fallback needed).
// 16 blocks x 256 thr; wave = 16 i-rows x all 1024 j; 16 phases x 64
// codes double-buffered. (unchanged from R12 - passed, fast)
// =====================================================================
__global__ __launch_bounds__(256) void k_cb(const float* __restrict__ w,
                                            float* __restrict__ wsf,
                                            float* __restrict__ out) {
  __shared__ unsigned short Lw[2][16384];  // per buf: wh[0..8191], wl[8192..]
  __shared__ float Lww[1024];
  const int t    = threadIdx.x;
  const int lane = t & 63;
  const int wq   = t >> 6;       // wave id 0..3
  const int n    = lane & 15;
  const int q    = lane >> 4;
  const int i0   = blockIdx.x * 64 + wq * 16;   // wave's 16 rows

  const unsigned short* whg = (const unsigned short*)(out + SCR);
  const unsigned short* wlg = (const unsigned short*)(out + SCR_WL);

#define CSTAGE(BUF, P) do {                                              \
    const unsigned short* _wh = whg + (size_t)(P) * 8192;                \
    const unsigned short* _wl = wlg + (size_t)(P) * 8192;                \
    _Pragma("unroll")                                                    \
    for (int _it = 0; _it < 4; ++_it) {                                  \
      int _ci = _it * 256 + t;                                           \
      GLDS16(_wh + _ci * 8, &Lw[BUF][_ci * 8]);                          \
      GLDS16(_wl + _ci * 8, &Lw[BUF][8192 + _ci * 8]);                   \
    } } while (0)

  CSTAGE(0, 0);
  for (int i = t; i < 1024; i += 256) Lww[i] = wsf[WS_WW + i];

  // A-frags: w row (i0 + n) as bf16 hi/lo, 4 K-slices
  s16x8 AH[4], AL[4];
  {
    const float* wr = w + (size_t)(i0 + n) * D;
#pragma unroll
    for (int ks = 0; ks < 4; ++ks) {
      float4 f0 = *(const float4*)(wr + ks * 32 + q * 8);
      float4 f1 = *(const float4*)(wr + ks * 32 + q * 8 + 4);
      float ff[8] = {f0.x, f0.y, f0.z, f0.w, f1.x, f1.y, f1.z, f1.w};
      s16x8 h, l;
#pragma unroll
      for (int j = 0; j < 8; ++j) {
        unsigned short hb = f2bf(ff[j]);
        h[j] = (short)hb;
        l[j] = (short)f2bf(ff[j] - bf2f(hb));
      }
      AH[ks] = h; AL[ks] = l;
    }
  }
  float wwi[4];
#pragma unroll
  for (int r = 0; r < 4; ++r) wwi[r] = wsf[WS_WW + i0 + q * 4 + r];

  float m1[4], m2[4], S[4], Q[4];
#pragma unroll
  for (int r = 0; r < 4; ++r) { m1[r] = INFINITY; m2[r] = INFINITY; S[r] = 0.f; Q[r] = 0.f; }

  __syncthreads();   // drains prologue stage + Lww

  for (int p = 0; p < 16; ++p) {
    const int buf = p & 1;
    if (p < 15) CSTAGE(buf ^ 1, p + 1);

    for (int ct = 0; ct < 4; ++ct) {
      const int cL = ct * 16 + n;
      const int c  = p * 64 + cL;
      const float wwj = Lww[c];
      f32x4 aX = (f32x4){0.f, 0.f, 0.f, 0.f};
      f32x4 aY = (f32x4){0.f, 0.f, 0.f, 0.f};
#pragma unroll
      for (int ks = 0; ks < 4; ++ks) {
        unsigned int off = (unsigned int)(cL * 256) +
                           (((unsigned int)(64 * ks + 16 * q)) ^ ((unsigned int)(cL & 15) << 4));
        s16x8 BH = *(const s16x8*)((const char*)&Lw[buf][0] + off);
        s16x8 BL = *(const s16x8*)((const char*)&Lw[buf][8192] + off);
        aX = __builtin_amdgcn_mfma_f32_16x16x32_bf16(AH[ks], BH, aX, 0, 0, 0);
        aY = __builtin_amdgcn_mfma_f32_16x16x32_bf16(AH[ks], BL, aY, 0, 0, 0);
        aY = __builtin_amdgcn_mfma_f32_16x16x32_bf16(AL[ks], BH, aY, 0, 0, 0);
      }
#pragma unroll
      for (int r = 0; r < 4; ++r) {
        float dot = aX[r] + aY[r];
        float d = __fsub_rn(__fadd_rn(wwi[r], wwj), __fmul_rn(2.f, dot));
        if (d < m1[r]) { m2[r] = m1[r]; m1[r] = d; } else m2[r] = fminf(m2[r], d);
        S[r] += d; Q[r] = fmaf(d, d, Q[r]);
      }
    }
    __syncthreads();
  }

  // reduce across the 16 lanes (n) holding each row
#pragma unroll
  for (int r = 0; r < 4; ++r) {
    float a1 = m1[r], a2 = m2[r], s = S[r], qq = Q[r];
#pragma unroll
    for (int mask = 1; mask < 16; mask <<= 1) {
      float b1 = __shfl_xor(a1, mask, 64);
      float b2 = __shfl_xor(a2, mask, 64);
      float bs = __shfl_xor(s,  mask, 64);
      float bq = __shfl_xor(qq, mask, 64);
      a2 = fminf(fminf(a2, b2), fmaxf(a1, b1));
      a1 = fminf(a1, b1);
      s += bs; qq += bq;
    }
    if (n == 0) {
      int row = i0 + q * 4 + r;
      wsf[WS_MIN2 + row] = a2;
      wsf[WS_VAR + row] = (qq - s * s / (float)NE) / (float)(NE - 1);
    }
  }
#undef CSTAGE
}

// =====================================================================
// k_qmfma v6: same 3-chain math/swizzle as R12, re-tiled for occupancy.
// 512 blocks x 256 thr (4 waves x 32 rows = 128 rows/block); 32 phases
// x 32 codes double-buffered -> LDS 36KB -> 4 blocks/CU -> 16 waves/CU
// (4/SIMD). 4 independent blocks per CU break the barrier lockstep so
// LDS-read, MFMA and epilogue-VALU pipes overlap across blocks.
// =====================================================================
__global__ __launch_bounds__(256, 4) void k_qmfma(const float* __restrict__ z,
                                                  float* __restrict__ wsf,
                                                  float* __restrict__ out) {
  __shared__ unsigned short Lw[2][8192];   // per buf: wh[0..4095], wl[4096..]
  __shared__ float Lww[1024];
  const int t    = threadIdx.x;
  const int lane = t & 63;
  const int wq   = t >> 6;       // wave id 0..3
  const int n    = lane & 15;    // col / A-row index
  const int q    = lane >> 4;    // quad 0..3
  const int rowb = blockIdx.x * 128 + wq * 32;

  const unsigned short* whg = (const unsigned short*)(out + SCR);
  const unsigned short* wlg = (const unsigned short*)(out + SCR_WL);

#define QSTAGE(BUF, P) do {                                              \
    const unsigned short* _wh = whg + (size_t)(P) * 4096;                \
    const unsigned short* _wl = wlg + (size_t)(P) * 4096;                \
    _Pragma("unroll")                                                    \
    for (int _it = 0; _it < 2; ++_it) {                                  \
      int _ci = _it * 256 + t;                                           \
      GLDS16(_wh + _ci * 8, &Lw[BUF][_ci * 8]);                          \
      GLDS16(_wl + _ci * 8, &Lw[BUF][4096 + _ci * 8]);                   \
    } } while (0)

  QSTAGE(0, 0);                                   // prologue stage
  for (int i = t; i < 1024; i += 256) Lww[i] = wsf[WS_WW + i];

  // ---- A-frags: z rows as bf16 hi/lo (2 rowtiles x 4 K-slices) ----
  s16x8 AH[2][4], AL[2][4];
#pragma unroll
  for (int rt = 0; rt < 2; ++rt) {
    const float* zr = z + (size_t)(rowb + rt * 16 + n) * D;
#pragma unroll
    for (int ks = 0; ks < 4; ++ks) {
      float4 f0 = *(const float4*)(zr + ks * 32 + q * 8);
      float4 f1 = *(const float4*)(zr + ks * 32 + q * 8 + 4);
      float ff[8] = {f0.x, f0.y, f0.z, f0.w, f1.x, f1.y, f1.z, f1.w};
      s16x8 h, l;
#pragma unroll
      for (int j = 0; j < 8; ++j) {
        unsigned short hb = f2bf(ff[j]);
        h[j] = (short)hb;
        l[j] = (short)f2bf(ff[j] - bf2f(hb));
      }
      AH[rt][ks] = h; AL[rt][ks] = l;
    }
  }

  float m1[2][4], m2[2][4]; int i1[2][4];
#pragma unroll
  for (int rt = 0; rt < 2; ++rt)
#pragma unroll
    for (int r = 0; r < 4; ++r) { m1[rt][r] = INFINITY; m2[rt][r] = INFINITY; i1[rt][r] = 0; }

  __syncthreads();   // drains prologue stage (vmcnt) + Lww writes

  for (int p = 0; p < 32; ++p) {
    const int buf = p & 1;
    if (p < 31) QSTAGE(buf ^ 1, p + 1);     // issue next phase's loads early

    for (int ct = 0; ct < 2; ++ct) {
      const int cL = ct * 16 + n;           // phase-local code 0..31
      const int c  = p * 32 + cL;           // global code
      const float wwc = Lww[c];
      f32x4 aX[2], aY[2];
#pragma unroll
      for (int rt = 0; rt < 2; ++rt) {
        aX[rt] = (f32x4){0.f, 0.f, 0.f, 0.f};
        aY[rt] = (f32x4){0.f, 0.f, 0.f, 0.f};
      }
#pragma unroll
      for (int ks = 0; ks < 4; ++ks) {
        unsigned int off = (unsigned int)(cL * 256) +
                           (((unsigned int)(64 * ks + 16 * q)) ^ ((unsigned int)(cL & 15) << 4));
        s16x8 BH = *(const s16x8*)((const char*)&Lw[buf][0] + off);
        s16x8 BL = *(const s16x8*)((const char*)&Lw[buf][4096] + off);
#pragma unroll
        for (int rt = 0; rt < 2; ++rt) {
          aX[rt] = __builtin_amdgcn_mfma_f32_16x16x32_bf16(AH[rt][ks], BH, aX[rt], 0, 0, 0);
          aY[rt] = __builtin_amdgcn_mfma_f32_16x16x32_bf16(AH[rt][ks], BL, aY[rt], 0, 0, 0);
          aY[rt] = __builtin_amdgcn_mfma_f32_16x16x32_bf16(AL[rt][ks], BH, aY[rt], 0, 0, 0);
        }
      }
#pragma unroll
      for (int rt = 0; rt < 2; ++rt)
#pragma unroll
        for (int r = 0; r < 4; ++r) {
          float v = fmaf(-2.f, aX[rt][r] + aY[rt][r], wwc);  // s = ww - 2*dot
          if (v < m1[rt][r]) { m2[rt][r] = m1[rt][r]; m1[rt][r] = v; i1[rt][r] = c; }
          else m2[rt][r] = fminf(m2[rt][r], v);
        }
    }
    __syncthreads();   // drains stage(p+1) vmcnt; all waves done with buf
  }

  // ---- reduce (m1,m2,i1) across the 16 lanes holding each row ----
#pragma unroll
  for (int rt = 0; rt < 2; ++rt)
#pragma unroll
    for (int r = 0; r < 4; ++r) {
      float a1 = m1[rt][r], a2 = m2[rt][r]; int ai = i1[rt][r];
#pragma unroll
      for (int mask = 1; mask < 16; mask <<= 1) {
        float b1 = __shfl_xor(a1, mask, 64);
        float b2 = __shfl_xor(a2, mask, 64);
        int   bi = __shfl_xor(ai, mask, 64);
        a2 = fminf(fminf(a2, b2), fmaxf(a1, b1));
        bool take = (b1 < a1) || (b1 == a1 && bi < ai);
        a1 = take ? b1 : a1; ai = take ? bi : ai;
      }
      if (n == 0) {
        int grow = rowb + rt * 16 + q * 4 + r;   // D row = (lane>>4)*4 + reg
        if (a2 - a1 > MARGIN) {
          ((int*)wsf)[WS_IDX + grow] = ai;
          out[OUT_IDX + grow] = (float)ai;
          out[OUT_SI  + grow] = (float)ai;
          ((int*)wsf)[WS_FLAGS + ai] = 1;
        } else {
          int pos = atomicAdd(((int*)out) + SCR_CNT, 1);
          ((int*)out)[SCR_LIST + pos] = grow;    // exact fp32 fallback row
        }
      }
    }
#undef QSTAGE
}

// ---- exact fp32 fallback over the compact flagged-row list ----
__global__ __launch_bounds__(256) void k_fallback(const float* __restrict__ z,
                                                  const float* __restrict__ w,
                                                  float* __restrict__ wsf,
                                                  float* __restrict__ out) {
  const int t = threadIdx.x;
  const int count = ((const int*)out)[SCR_CNT];
  const int* list = ((const int*)out) + SCR_LIST;
  __shared__ float zrow[128];
  __shared__ float zzs;
  __shared__ float rv[256];
  __shared__ int   ri[256];
  for (int i = blockIdx.x; i < count; i += gridDim.x) {
    int row = list[i];
    __syncthreads();   // protect zrow/zzs reuse across iterations
    if (t < 32) ((float4*)zrow)[t] = ((const float4*)(z + (size_t)row * D))[t];
    __syncthreads();
    // exact numpy pairwise zz: lane m owns a[m] (k%8==m), then exact tree
    if (t < 8) {
      float a = __fmul_rn(zrow[t], zrow[t]);
#pragma unroll
      for (int k = 8; k < 128; k += 8)
        a = __fadd_rn(a, __fmul_rn(zrow[k + t], zrow[k + t]));
      float s1 = __fadd_rn(a,  __shfl_xor(a, 1, 64));
      float s2 = __fadd_rn(s1, __shfl_xor(s1, 2, 64));
      float s3 = __fadd_rn(s2, __shfl_xor(s2, 4, 64));
      if (t == 0) zzs = s3;
    }
    __syncthreads();
    float zz = zzs;
    float bv = INFINITY; int bi = 0;
    const float4* z4 = (const float4*)zrow;
    for (int cc = 0; cc < 4; ++cc) {
      int c = cc * 256 + t;             // ascending per thread
      const float4* wp = (const float4*)(w + (size_t)c * D);
      float acc = 0.f;
#pragma unroll
      for (int k4 = 0; k4 < 32; ++k4) {
        float4 a = wp[k4];
        float4 zv = z4[k4];
        acc = fmaf(zv.x, a.x, acc); acc = fmaf(zv.y, a.y, acc);
        acc = fmaf(zv.z, a.z, acc); acc = fmaf(zv.w, a.w, acc);
      }
      float d = __fsub_rn(__fadd_rn(zz, wsf[WS_WW + c]), __fmul_rn(2.f, acc));
      if (d < bv) { bv = d; bi = c; }
    }
    rv[t] = bv; ri[t] = bi;
    __syncthreads();
    for (int s = 128; s > 0; s >>= 1) {
      if (t < s) {
        float v2 = rv[t + s]; int i2 = ri[t + s];
        if (v2 < rv[t] || (v2 == rv[t] && i2 < ri[t])) { rv[t] = v2; ri[t] = i2; }
      }
      __syncthreads();
    }
    if (t == 0) {
      int mi = ri[0];
      ((int*)wsf)[WS_IDX + row] = mi;
      out[OUT_IDX + row] = (float)mi;
      out[OUT_SI  + row] = (float)mi;
      ((int*)wsf)[WS_FLAGS + mi] = 1;
    }
  }
}

// ---- gather z_q -> out0, loss partials, per-column square partials ----
__global__ __launch_bounds__(256) void k_gather(const float* __restrict__ z,
                                                const float* __restrict__ w,
                                                float* __restrict__ ws,
                                                float* __restrict__ out) {
  __shared__ float csp[32][8][4];
  __shared__ float lred[256];
  const int t = threadIdx.x, blk = blockIdx.x;
  const int c4 = t & 31, rg = t >> 5;
  float lp = 0.f;
  float csx = 0.f, csy = 0.f, csz = 0.f, csw = 0.f;
  for (int m = 0; m < 16; ++m) {
    int r  = rg + 8 * m;
    int gr = blk * 128 + r;
    int idx = ((const int*)ws)[WS_IDX + gr];
    float4 qv = *(const float4*)&w[idx * D + c4 * 4];
    float4 zv = *(const float4*)&z[(size_t)gr * D + c4 * 4];
    *(float4*)&out[OUT_ZQ + (size_t)gr * D + c4 * 4] = qv;
    float dx = qv.x - zv.x, dy = qv.y - zv.y, dz = qv.z - zv.z, dw = qv.w - zv.w;
    lp = fmaf(dx, dx, lp); lp = fmaf(dy, dy, lp);
    lp = fmaf(dz, dz, lp); lp = fmaf(dw, dw, lp);
    csx = fmaf(qv.x, qv.x, csx); csy = fmaf(qv.y, qv.y, csy);
    csz = fmaf(qv.z, qv.z, csz); csw = fmaf(qv.w, qv.w, csw);
  }
  csp[c4][rg][0] = csx; csp[c4][rg][1] = csy;
  csp[c4][rg][2] = csz; csp[c4][rg][3] = csw;
  lred[t] = lp;
  __syncthreads();
  for (int s = 128; s > 0; s >>= 1) {
    if (t < s) lred[t] += lred[t + s];
    __syncthreads();
  }
  if (t == 0) ws[WS_LOSSP + blk] = lred[0];
  if (t < 128) {
    int dcol = t;
    float s = 0.f;
    for (int g = 0; g < 8; ++g) s += csp[dcol >> 2][g][dcol & 3];
    ws[WS_COLSQP + blk * 128 + dcol] = s;
  }
}

// ---- zn (regather) + inline colsq combine + final scalars (block 0) ----
__global__ __launch_bounds__(256) void k_zn(const float* __restrict__ ws,
                                            const float* __restrict__ w,
                                            float* __restrict__ out) {
  const int t = threadIdx.x, blk = blockIdx.x;
  const int c4 = t & 31, rg = t >> 5;
  const int b = blk >> 5;                  // 32 row-blocks per batch
  float csx = 0.f, csy = 0.f, csz = 0.f, csw = 0.f;
  for (int rb = 0; rb < 32; ++rb) {
    float4 pp = *(const float4*)&ws[WS_COLSQP + (size_t)(b * 32 + rb) * 128 + c4 * 4];
    csx += pp.x; csy += pp.y; csz += pp.z; csw += pp.w;
  }
  float nx = fmaxf(sqrtf(csx), 1e-12f);
  float ny = fmaxf(sqrtf(csy), 1e-12f);
  float nz = fmaxf(sqrtf(csz), 1e-12f);
  float nw = fmaxf(sqrtf(csw), 1e-12f);
  for (int m = 0; m < 16; ++m) {
    int gr = blk * 128 + rg + 8 * m;
    int idx = ((const int*)ws)[WS_IDX + gr];
    float4 qv = *(const float4*)&w[idx * D + c4 * 4];
    size_t o = (size_t)gr * D + c4 * 4;
    out[OUT_ZN + o + 0] = qv.x / nx;
    out[OUT_ZN + o + 1] = qv.y / ny;
    out[OUT_ZN + o + 2] = qv.z / nz;
    out[OUT_ZN + o + 3] = qv.w / nw;
  }
  // ---- block 0: final scalars + sampled_idx
  if (blk == 0) {
    __shared__ float f1[256], f2[256], f3[256];
    __syncthreads();
    f1[t] = ws[WS_LOSSP + t] + ws[WS_LOSSP + t + 256];
    f2[t] = (ws[WS_MIN2 + t] + ws[WS_MIN2 + t + 512]) +
            (ws[WS_MIN2 + t + 256] + ws[WS_MIN2 + t + 768]);
    f3[t] = (ws[WS_VAR + t] + ws[WS_VAR + t + 512]) +
            (ws[WS_VAR + t + 256] + ws[WS_VAR + t + 768]);
    __syncthreads();
    for (int s = 128; s > 0; s >>= 1) {
      if (t < s) { f1[t] += f1[t + s]; f2[t] += f2[t + s]; f3[t] += f3[t + s]; }
      __syncthreads();
    }
    if (t == 0) {
      float m = f1[0] / 8388608.f;            // mean((z_q - z)^2)
      out[OUT_LOSS] = m + 0.9f * m;           // + BETA * same
      out[OUT_VAR]  = f3[0] / 1024.f;
      out[OUT_DIST] = f2[0] / 1024.f;
    }
    const int* flags = (const int*)ws + WS_FLAGS;
    for (int i = t; i < NB * NE; i += 256)
      out[OUT_SAMP + i] = (i < NE && flags[i] != 0) ? 1.f : 0.f;
  }
}

extern "C" void kernel_launch(void* const* d_in, const int* in_sizes, int n_in,
                              void* d_out, int out_size, void* d_ws, size_t ws_size,
                              hipStream_t stream) {
  const float* z = (const float*)d_in[0];
  const float* w = (const float*)d_in[1];
  float* out = (float*)d_out;
  float* ws  = (float*)d_ws;

  hipLaunchKernelGGL(k_wsplit,   dim3(64),   dim3(256), 0, stream, w, out, ws);
  hipLaunchKernelGGL(k_cb,       dim3(16),   dim3(256), 0, stream, w, ws, out);
  hipLaunchKernelGGL(k_qmfma,    dim3(512),  dim3(256), 0, stream, z, ws, out);
  hipLaunchKernelGGL(k_fallback, dim3(1024), dim3(256), 0, stream, z, w, ws, out);
  hipLaunchKernelGGL(k_gather,   dim3(512),  dim3(256), 0, stream, z, w, ws, out);
  hipLaunchKernelGGL(k_zn,       dim3(512),  dim3(256), 0, stream, ws, w, out);
}

// Round 14
// 134.052 us; speedup vs baseline: 1.1321x; 1.1321x over previous
//
#include <hip/hip_runtime.h>
#include <math.h>

// Problem constants (z: [16,4096,128] f32, emb_w: [1024,128] f32, unit rows)
#define D       128
#define NE      1024
#define NROWS   65536   // B*N
#define NB      16

// ---- output float offsets (total 16,924,675 floats) ----
#define OUT_ZQ    0            // [16,4096,128]
#define OUT_LOSS  8388608      // scalar
#define OUT_SAMP  8388609      // [16,1024]
#define OUT_IDX   8404993      // [16,4096] (float)
#define OUT_VAR   8470529      // scalar
#define OUT_DIST  8470530      // scalar
#define OUT_SI    8470531      // [16,4096] (float)
#define OUT_ZN    8536067      // [16,4096,128]  (overwritten LAST by k_zn)

// Scratch inside the OUT_ZN region (k_zn overwrites it at the very end).
#define SCR       8536068         // wh: 131072 ushorts (256KB)
#define SCR_WL    (SCR + 65536)   // wl: 131072 ushorts (256KB)
#define SCR_CNT   (SCR + 131072)  // int counter (zeroed by k_wsplit)
#define SCR_LIST  (SCR + 131073)  // int[<=65536] flagged-row list

// ---- workspace float offsets (538 KB total) ----
#define WS_IDX    0            // int[65536]
#define WS_WW     65536        // float[1024]
#define WS_FLAGS  66560        // int[1024]
#define WS_MIN2   67584        // float[1024]
#define WS_VAR    68608        // float[1024]
#define WS_LOSSP  69632        // float[512]
#define WS_COLSQP 70144        // float[512*128]
#define WS_COLSQ  135680       // float[16*128] (unused, kept for layout)

#define MARGIN 2e-3f

typedef __attribute__((ext_vector_type(8))) short s16x8;   // 8 bf16 (4 VGPR)
typedef __attribute__((ext_vector_type(4))) float f32x4;

#define GLDS16(gp, lp)                                                        \
  __builtin_amdgcn_global_load_lds(                                           \
      (const __attribute__((address_space(1))) unsigned int*)(gp),            \
      (__attribute__((address_space(3))) unsigned int*)(lp), 16, 0, 0)

__device__ __forceinline__ unsigned short f2bf(float f) {  // bf16 RNE
  unsigned int u = __float_as_uint(f);
  return (unsigned short)((u + 0x7FFFu + ((u >> 16) & 1u)) >> 16);
}
__device__ __forceinline__ float bf2f(unsigned short h) {
  return __uint_as_float(((unsigned int)h) << 16);
}

// numpy pairwise sum of squares over 128 contiguous floats (exact ref order).
__device__ __forceinline__ float npsq_sum128(const float* p) {
  float a[8];
#pragma unroll
  for (int m = 0; m < 8; ++m) a[m] = __fmul_rn(p[m], p[m]);
  for (int k = 8; k < 128; k += 8) {
#pragma unroll
    for (int m = 0; m < 8; ++m) a[m] = __fadd_rn(a[m], __fmul_rn(p[k + m], p[k + m]));
  }
  float s01 = __fadd_rn(a[0], a[1]);
  float s23 = __fadd_rn(a[2], a[3]);
  float s45 = __fadd_rn(a[4], a[5]);
  float s67 = __fadd_rn(a[6], a[7]);
  return __fadd_rn(__fadd_rn(s01, s23), __fadd_rn(s45, s67));
}

// ---- split w into bf16 hi/lo (full 4-bit XOR swizzle) + ww; also zero
// the flags array and the fallback counter (replaces both memsets). ----
// byte(c,k) = (c*256 + 2k) ^ ((c&15)<<4): 16B chunks -> 16B chunks.
__global__ __launch_bounds__(256) void k_wsplit(const float* __restrict__ w,
                                                float* __restrict__ out,
                                                float* __restrict__ ws) {
  int u = blockIdx.x * 256 + threadIdx.x;   // 16384 = 1024 codes x 16 octets
  int c = u >> 4, j = u & 15;
  const float4* p = (const float4*)(w + c * D + j * 8);
  float4 f0 = p[0], f1 = p[1];
  float ff[8] = {f0.x, f0.y, f0.z, f0.w, f1.x, f1.y, f1.z, f1.w};
  s16x8 h, l;
#pragma unroll
  for (int e = 0; e < 8; ++e) {
    unsigned short hb = f2bf(ff[e]);
    h[e] = (short)hb;
    l[e] = (short)f2bf(ff[e] - bf2f(hb));
  }
  unsigned int by = ((unsigned int)(c * 256 + j * 16)) ^ ((unsigned int)((c & 15) << 4));
  *(s16x8*)((char*)(out + SCR) + by)    = h;
  *(s16x8*)((char*)(out + SCR_WL) + by) = l;
  if (u < NE) {
    ws[WS_WW + u] = npsq_sum128(w + u * D);   // fused k_ww
    ((int*)ws)[WS_FLAGS + u] = 0;             // replaces memset #1
  }
  if (u == 0) ((int*)out)[SCR_CNT] = 0;       // replaces memset #2
}

// =====================================================================
// k_cb v3: codebook self-distance stats via 3-chain hi/lo MFMA
// (tolerance-checked scalar outputs -> no margin/fallback needed).
// 16 blocks x 256 thr; wave = 16 i-rows x all 1024 j; 16 phases x 64
// codes double-buffered. (unchanged from R12 - passed, fast)
// =====================================================================
__global__ __launch_bounds__(256) void k_cb(const float* __restrict__ w,
                                            float* __restrict__ wsf,
                                            float* __restrict__ out) {
  __shared__ unsigned short Lw[2][16384];  // per buf: wh[0..8191], wl[8192..]
  __shared__ float Lww[1024];
  const int t    = threadIdx.x;
  const int lane = t & 63;
  const int wq   = t >> 6;       // wave id 0..3
  const int n    = lane & 15;
  const int q    = lane >> 4;
  const int i0   = blockIdx.x * 64 + wq * 16;   // wave's 16 rows

  const unsigned short* whg = (const unsigned short*)(out + SCR);
  const unsigned short* wlg = (const unsigned short*)(out + SCR_WL);

#define CSTAGE(BUF, P) do {                                              \
    const unsigned short* _wh = whg + (size_t)(P) * 8192;                \
    const unsigned short* _wl = wlg + (size_t)(P) * 8192;                \
    _Pragma("unroll")                                                    \
    for (int _it = 0; _it < 4; ++_it) {                                  \
      int _ci = _it * 256 + t;                                           \
      GLDS16(_wh + _ci * 8, &Lw[BUF][_ci * 8]);                          \
      GLDS16(_wl + _ci * 8, &Lw[BUF][8192 + _ci * 8]);                   \
    } } while (0)

  CSTAGE(0, 0);
  for (int i = t; i < 1024; i += 256) Lww[i] = wsf[WS_WW + i];

  // A-frags: w row (i0 + n) as bf16 hi/lo, 4 K-slices
  s16x8 AH[4], AL[4];
  {
    const float* wr = w + (size_t)(i0 + n) * D;
#pragma unroll
    for (int ks = 0; ks < 4; ++ks) {
      float4 f0 = *(const float4*)(wr + ks * 32 + q * 8);
      float4 f1 = *(const float4*)(wr + ks * 32 + q * 8 + 4);
      float ff[8] = {f0.x, f0.y, f0.z, f0.w, f1.x, f1.y, f1.z, f1.w};
      s16x8 h, l;
#pragma unroll
      for (int j = 0; j < 8; ++j) {
        unsigned short hb = f2bf(ff[j]);
        h[j] = (short)hb;
        l[j] = (short)f2bf(ff[j] - bf2f(hb));
      }
      AH[ks] = h; AL[ks] = l;
    }
  }
  float wwi[4];
#pragma unroll
  for (int r = 0; r < 4; ++r) wwi[r] = wsf[WS_WW + i0 + q * 4 + r];

  float m1[4], m2[4], S[4], Q[4];
#pragma unroll
  for (int r = 0; r < 4; ++r) { m1[r] = INFINITY; m2[r] = INFINITY; S[r] = 0.f; Q[r] = 0.f; }

  __syncthreads();   // drains prologue stage + Lww

  for (int p = 0; p < 16; ++p) {
    const int buf = p & 1;
    if (p < 15) CSTAGE(buf ^ 1, p + 1);

    for (int ct = 0; ct < 4; ++ct) {
      const int cL = ct * 16 + n;
      const int c  = p * 64 + cL;
      const float wwj = Lww[c];
      f32x4 aX = (f32x4){0.f, 0.f, 0.f, 0.f};
      f32x4 aY = (f32x4){0.f, 0.f, 0.f, 0.f};
#pragma unroll
      for (int ks = 0; ks < 4; ++ks) {
        unsigned int off = (unsigned int)(cL * 256) +
                           (((unsigned int)(64 * ks + 16 * q)) ^ ((unsigned int)(cL & 15) << 4));
        s16x8 BH = *(const s16x8*)((const char*)&Lw[buf][0] + off);
        s16x8 BL = *(const s16x8*)((const char*)&Lw[buf][8192] + off);
        aX = __builtin_amdgcn_mfma_f32_16x16x32_bf16(AH[ks], BH, aX, 0, 0, 0);
        aY = __builtin_amdgcn_mfma_f32_16x16x32_bf16(AH[ks], BL, aY, 0, 0, 0);
        aY = __builtin_amdgcn_mfma_f32_16x16x32_bf16(AL[ks], BH, aY, 0, 0, 0);
      }
#pragma unroll
      for (int r = 0; r < 4; ++r) {
        float dot = aX[r] + aY[r];
        float d = __fsub_rn(__fadd_rn(wwi[r], wwj), __fmul_rn(2.f, dot));
        if (d < m1[r]) { m2[r] = m1[r]; m1[r] = d; } else m2[r] = fminf(m2[r], d);
        S[r] += d; Q[r] = fmaf(d, d, Q[r]);
      }
    }
    __syncthreads();
  }

  // reduce across the 16 lanes (n) holding each row
#pragma unroll
  for (int r = 0; r < 4; ++r) {
    float a1 = m1[r], a2 = m2[r], s = S[r], qq = Q[r];
#pragma unroll
    for (int mask = 1; mask < 16; mask <<= 1) {
      float b1 = __shfl_xor(a1, mask, 64);
      float b2 = __shfl_xor(a2, mask, 64);
      float bs = __shfl_xor(s,  mask, 64);
      float bq = __shfl_xor(qq, mask, 64);
      a2 = fminf(fminf(a2, b2), fmaxf(a1, b1));
      a1 = fminf(a1, b1);
      s += bs; qq += bq;
    }
    if (n == 0) {
      int row = i0 + q * 4 + r;
      wsf[WS_MIN2 + row] = a2;
      wsf[WS_VAR + row] = (qq - s * s / (float)NE) / (float)(NE - 1);
    }
  }
#undef CSTAGE
}

// =====================================================================
// k_qmfma v7: R13 body with launch_bounds(256,2) - do NOT pin occupancy
// (R13's (256,4) hard-capped VGPR at 128 and spilled to scratch).
// 512 blocks x 256 thr (4 waves x 32 rows); 32 phases x 32 codes
// double-buffered, LDS 36KB. Residency emerges: LDS allows 4 blocks/CU,
// VGPR ~116 allows 4 waves/SIMD -> 16 waves/CU, 4 independent blocks.
// =====================================================================
__global__ __launch_bounds__(256, 2) void k_qmfma(const float* __restrict__ z,
                                                  float* __restrict__ wsf,
                                                  float* __restrict__ out) {
  __shared__ unsigned short Lw[2][8192];   // per buf: wh[0..4095], wl[4096..]
  __shared__ float Lww[1024];
  const int t    = threadIdx.x;
  const int lane = t & 63;
  const int wq   = t >> 6;       // wave id 0..3
  const int n    = lane & 15;    // col / A-row index
  const int q    = lane >> 4;    // quad 0..3
  const int rowb = blockIdx.x * 128 + wq * 32;

  const unsigned short* whg = (const unsigned short*)(out + SCR);
  const unsigned short* wlg = (const unsigned short*)(out + SCR_WL);

#define QSTAGE(BUF, P) do {                                              \
    const unsigned short* _wh = whg + (size_t)(P) * 4096;                \
    const unsigned short* _wl = wlg + (size_t)(P) * 4096;                \
    _Pragma("unroll")                                                    \
    for (int _it = 0; _it < 2; ++_it) {                                  \
      int _ci = _it * 256 + t;                                           \
      GLDS16(_wh + _ci * 8, &Lw[BUF][_ci * 8]);                          \
      GLDS16(_wl + _ci * 8, &Lw[BUF][4096 + _ci * 8]);                   \
    } } while (0)

  QSTAGE(0, 0);                                   // prologue stage
  for (int i = t; i < 1024; i += 256) Lww[i] = wsf[WS_WW + i];

  // ---- A-frags: z rows as bf16 hi/lo (2 rowtiles x 4 K-slices) ----
  s16x8 AH[2][4], AL[2][4];
#pragma unroll
  for (int rt = 0; rt < 2; ++rt) {
    const float* zr = z + (size_t)(rowb + rt * 16 + n) * D;
#pragma unroll
    for (int ks = 0; ks < 4; ++ks) {
      float4 f0 = *(const float4*)(zr + ks * 32 + q * 8);
      float4 f1 = *(const float4*)(zr + ks * 32 + q * 8 + 4);
      float ff[8] = {f0.x, f0.y, f0.z, f0.w, f1.x, f1.y, f1.z, f1.w};
      s16x8 h, l;
#pragma unroll
      for (int j = 0; j < 8; ++j) {
        unsigned short hb = f2bf(ff[j]);
        h[j] = (short)hb;
        l[j] = (short)f2bf(ff[j] - bf2f(hb));
      }
      AH[rt][ks] = h; AL[rt][ks] = l;
    }
  }

  float m1[2][4], m2[2][4]; int i1[2][4];
#pragma unroll
  for (int rt = 0; rt < 2; ++rt)
#pragma unroll
    for (int r = 0; r < 4; ++r) { m1[rt][r] = INFINITY; m2[rt][r] = INFINITY; i1[rt][r] = 0; }

  __syncthreads();   // drains prologue stage (vmcnt) + Lww writes

  for (int p = 0; p < 32; ++p) {
    const int buf = p & 1;
    if (p < 31) QSTAGE(buf ^ 1, p + 1);     // issue next phase's loads early

    for (int ct = 0; ct < 2; ++ct) {
      const int cL = ct * 16 + n;           // phase-local code 0..31
      const int c  = p * 32 + cL;           // global code
      const float wwc = Lww[c];
      f32x4 aX[2], aY[2];
#pragma unroll
      for (int rt = 0; rt < 2; ++rt) {
        aX[rt] = (f32x4){0.f, 0.f, 0.f, 0.f};
        aY[rt] = (f32x4){0.f, 0.f, 0.f, 0.f};
      }
#pragma unroll
      for (int ks = 0; ks < 4; ++ks) {
        unsigned int off = (unsigned int)(cL * 256) +
                           (((unsigned int)(64 * ks + 16 * q)) ^ ((unsigned int)(cL & 15) << 4));
        s16x8 BH = *(const s16x8*)((const char*)&Lw[buf][0] + off);
        s16x8 BL = *(const s16x8*)((const char*)&Lw[buf][4096] + off);
#pragma unroll
        for (int rt = 0; rt < 2; ++rt) {
          aX[rt] = __builtin_amdgcn_mfma_f32_16x16x32_bf16(AH[rt][ks], BH, aX[rt], 0, 0, 0);
          aY[rt] = __builtin_amdgcn_mfma_f32_16x16x32_bf16(AH[rt][ks], BL, aY[rt], 0, 0, 0);
          aY[rt] = __builtin_amdgcn_mfma_f32_16x16x32_bf16(AL[rt][ks], BH, aY[rt], 0, 0, 0);
        }
      }
#pragma unroll
      for (int rt = 0; rt < 2; ++rt)
#pragma unroll
        for (int r = 0; r < 4; ++r) {
          float v = fmaf(-2.f, aX[rt][r] + aY[rt][r], wwc);  // s = ww - 2*dot
          if (v < m1[rt][r]) { m2[rt][r] = m1[rt][r]; m1[rt][r] = v; i1[rt][r] = c; }
          else m2[rt][r] = fminf(m2[rt][r], v);
        }
    }
    __syncthreads();   // drains stage(p+1) vmcnt; all waves done with buf
  }

  // ---- reduce (m1,m2,i1) across the 16 lanes holding each row ----
#pragma unroll
  for (int rt = 0; rt < 2; ++rt)
#pragma unroll
    for (int r = 0; r < 4; ++r) {
      float a1 = m1[rt][r], a2 = m2[rt][r]; int ai = i1[rt][r];
#pragma unroll
      for (int mask = 1; mask < 16; mask <<= 1) {
        float b1 = __shfl_xor(a1, mask, 64);
        float b2 = __shfl_xor(a2, mask, 64);
        int   bi = __shfl_xor(ai, mask, 64);
        a2 = fminf(fminf(a2, b2), fmaxf(a1, b1));
        bool take = (b1 < a1) || (b1 == a1 && bi < ai);
        a1 = take ? b1 : a1; ai = take ? bi : ai;
      }
      if (n == 0) {
        int grow = rowb + rt * 16 + q * 4 + r;   // D row = (lane>>4)*4 + reg
        if (a2 - a1 > MARGIN) {
          ((int*)wsf)[WS_IDX + grow] = ai;
          out[OUT_IDX + grow] = (float)ai;
          out[OUT_SI  + grow] = (float)ai;
          ((int*)wsf)[WS_FLAGS + ai] = 1;
        } else {
          int pos = atomicAdd(((int*)out) + SCR_CNT, 1);
          ((int*)out)[SCR_LIST + pos] = grow;    // exact fp32 fallback row
        }
      }
    }
#undef QSTAGE
}

// ---- exact fp32 fallback over the compact flagged-row list ----
__global__ __launch_bounds__(256) void k_fallback(const float* __restrict__ z,
                                                  const float* __restrict__ w,
                                                  float* __restrict__ wsf,
                                                  float* __restrict__ out) {
  const int t = threadIdx.x;
  const int count = ((const int*)out)[SCR_CNT];
  const int* list = ((const int*)out) + SCR_LIST;
  __shared__ float zrow[128];
  __shared__ float zzs;
  __shared__ float rv[256];
  __shared__ int   ri[256];
  for (int i = blockIdx.x; i < count; i += gridDim.x) {
    int row = list[i];
    __syncthreads();   // protect zrow/zzs reuse across iterations
    if (t < 32) ((float4*)zrow)[t] = ((const float4*)(z + (size_t)row * D))[t];
    __syncthreads();
    // exact numpy pairwise zz: lane m owns a[m] (k%8==m), then exact tree
    if (t < 8) {
      float a = __fmul_rn(zrow[t], zrow[t]);
#pragma unroll
      for (int k = 8; k < 128; k += 8)
        a = __fadd_rn(a, __fmul_rn(zrow[k + t], zrow[k + t]));
      float s1 = __fadd_rn(a,  __shfl_xor(a, 1, 64));
      float s2 = __fadd_rn(s1, __shfl_xor(s1, 2, 64));
      float s3 = __fadd_rn(s2, __shfl_xor(s2, 4, 64));
      if (t == 0) zzs = s3;
    }
    __syncthreads();
    float zz = zzs;
    float bv = INFINITY; int bi = 0;
    const float4* z4 = (const float4*)zrow;
    for (int cc = 0; cc < 4; ++cc) {
      int c = cc * 256 + t;             // ascending per thread
      const float4* wp = (const float4*)(w + (size_t)c * D);
      float acc = 0.f;
#pragma unroll
      for (int k4 = 0; k4 < 32; ++k4) {
        float4 a = wp[k4];
        float4 zv = z4[k4];
        acc = fmaf(zv.x, a.x, acc); acc = fmaf(zv.y, a.y, acc);
        acc = fmaf(zv.z, a.z, acc); acc = fmaf(zv.w, a.w, acc);
      }
      float d = __fsub_rn(__fadd_rn(zz, wsf[WS_WW + c]), __fmul_rn(2.f, acc));
      if (d < bv) { bv = d; bi = c; }
    }
    rv[t] = bv; ri[t] = bi;
    __syncthreads();
    for (int s = 128; s > 0; s >>= 1) {
      if (t < s) {
        float v2 = rv[t + s]; int i2 = ri[t + s];
        if (v2 < rv[t] || (v2 == rv[t] && i2 < ri[t])) { rv[t] = v2; ri[t] = i2; }
      }
      __syncthreads();
    }
    if (t == 0) {
      int mi = ri[0];
      ((int*)wsf)[WS_IDX + row] = mi;
      out[OUT_IDX + row] = (float)mi;
      out[OUT_SI  + row] = (float)mi;
      ((int*)wsf)[WS_FLAGS + mi] = 1;
    }
  }
}

// ---- gather z_q -> out0, loss partials, per-column square partials ----
__global__ __launch_bounds__(256) void k_gather(const float* __restrict__ z,
                                                const float* __restrict__ w,
                                                float* __restrict__ ws,
                                                float* __restrict__ out) {
  __shared__ float csp[32][8][4];
  __shared__ float lred[256];
  const int t = threadIdx.x, blk = blockIdx.x;
  const int c4 = t & 31, rg = t >> 5;
  float lp = 0.f;
  float csx = 0.f, csy = 0.f, csz = 0.f, csw = 0.f;
  for (int m = 0; m < 16; ++m) {
    int r  = rg + 8 * m;
    int gr = blk * 128 + r;
    int idx = ((const int*)ws)[WS_IDX + gr];
    float4 qv = *(const float4*)&w[idx * D + c4 * 4];
    float4 zv = *(const float4*)&z[(size_t)gr * D + c4 * 4];
    *(float4*)&out[OUT_ZQ + (size_t)gr * D + c4 * 4] = qv;
    float dx = qv.x - zv.x, dy = qv.y - zv.y, dz = qv.z - zv.z, dw = qv.w - zv.w;
    lp = fmaf(dx, dx, lp); lp = fmaf(dy, dy, lp);
    lp = fmaf(dz, dz, lp); lp = fmaf(dw, dw, lp);
    csx = fmaf(qv.x, qv.x, csx); csy = fmaf(qv.y, qv.y, csy);
    csz = fmaf(qv.z, qv.z, csz); csw = fmaf(qv.w, qv.w, csw);
  }
  csp[c4][rg][0] = csx; csp[c4][rg][1] = csy;
  csp[c4][rg][2] = csz; csp[c4][rg][3] = csw;
  lred[t] = lp;
  __syncthreads();
  for (int s = 128; s > 0; s >>= 1) {
    if (t < s) lred[t] += lred[t + s];
    __syncthreads();
  }
  if (t == 0) ws[WS_LOSSP + blk] = lred[0];
  if (t < 128) {
    int dcol = t;
    float s = 0.f;
    for (int g = 0; g < 8; ++g) s += csp[dcol >> 2][g][dcol & 3];
    ws[WS_COLSQP + blk * 128 + dcol] = s;
  }
}

// ---- zn (regather) + inline colsq combine + final scalars (block 0) ----
__global__ __launch_bounds__(256) void k_zn(const float* __restrict__ ws,
                                            const float* __restrict__ w,
                                            float* __restrict__ out) {
  const int t = threadIdx.x, blk = blockIdx.x;
  const int c4 = t & 31, rg = t >> 5;
  const int b = blk >> 5;                  // 32 row-blocks per batch
  float csx = 0.f, csy = 0.f, csz = 0.f, csw = 0.f;
  for (int rb = 0; rb < 32; ++rb) {
    float4 pp = *(const float4*)&ws[WS_COLSQP + (size_t)(b * 32 + rb) * 128 + c4 * 4];
    csx += pp.x; csy += pp.y; csz += pp.z; csw += pp.w;
  }
  float nx = fmaxf(sqrtf(csx), 1e-12f);
  float ny = fmaxf(sqrtf(csy), 1e-12f);
  float nz = fmaxf(sqrtf(csz), 1e-12f);
  float nw = fmaxf(sqrtf(csw), 1e-12f);
  for (int m = 0; m < 16; ++m) {
    int gr = blk * 128 + rg + 8 * m;
    int idx = ((const int*)ws)[WS_IDX + gr];
    float4 qv = *(const float4*)&w[idx * D + c4 * 4];
    size_t o = (size_t)gr * D + c4 * 4;
    out[OUT_ZN + o + 0] = qv.x / nx;
    out[OUT_ZN + o + 1] = qv.y / ny;
    out[OUT_ZN + o + 2] = qv.z / nz;
    out[OUT_ZN + o + 3] = qv.w / nw;
  }
  // ---- block 0: final scalars + sampled_idx
  if (blk == 0) {
    __shared__ float f1[256], f2[256], f3[256];
    __syncthreads();
    f1[t] = ws[WS_LOSSP + t] + ws[WS_LOSSP + t + 256];
    f2[t] = (ws[WS_MIN2 + t] + ws[WS_MIN2 + t + 512]) +
            (ws[WS_MIN2 + t + 256] + ws[WS_MIN2 + t + 768]);
    f3[t] = (ws[WS_VAR + t] + ws[WS_VAR + t + 512]) +
            (ws[WS_VAR + t + 256] + ws[WS_VAR + t + 768]);
    __syncthreads();
    for (int s = 128; s > 0; s >>= 1) {
      if (t < s) { f1[t] += f1[t + s]; f2[t] += f2[t + s]; f3[t] += f3[t + s]; }
      __syncthreads();
    }
    if (t == 0) {
      float m = f1[0] / 8388608.f;            // mean((z_q - z)^2)
      out[OUT_LOSS] = m + 0.9f * m;           // + BETA * same
      out[OUT_VAR]  = f3[0] / 1024.f;
      out[OUT_DIST] = f2[0] / 1024.f;
    }
    const int* flags = (const int*)ws + WS_FLAGS;
    for (int i = t; i < NB * NE; i += 256)
      out[OUT_SAMP + i] = (i < NE && flags[i] != 0) ? 1.f : 0.f;
  }
}

extern "C" void kernel_launch(void* const* d_in, const int* in_sizes, int n_in,
                              void* d_out, int out_size, void* d_ws, size_t ws_size,
                              hipStream_t stream) {
  const float* z = (const float*)d_in[0];
  const float* w = (const float*)d_in[1];
  float* out = (float*)d_out;
  float* ws  = (float*)d_ws;

  hipLaunchKernelGGL(k_wsplit,   dim3(64),   dim3(256), 0, stream, w, out, ws);
  hipLaunchKernelGGL(k_cb,       dim3(16),   dim3(256), 0, stream, w, ws, out);
  hipLaunchKernelGGL(k_qmfma,    dim3(512),  dim3(256), 0, stream, z, ws, out);
  hipLaunchKernelGGL(k_fallback, dim3(1024), dim3(256), 0, stream, z, w, ws, out);
  hipLaunchKernelGGL(k_gather,   dim3(512),  dim3(256), 0, stream, z, w, ws, out);
  hipLaunchKernelGGL(k_zn,       dim3(512),  dim3(256), 0, stream, ws, w, out);
}